// Round 1
// baseline (1007.809 us; speedup 1.0000x reference)
//
#include <hip/hip_runtime.h>
#include <math.h>

#define B 64
#define N 2048
#define D 512
#define KG 80
#define K 64

// ---------------------------------------------------------------------------
// Pass A: logits = x @ clusters; BN affine; softmax over 80; keep first 64.
// Writes assignment [B,N,64] and accumulates a_sum [B,64].
// Block: 256 threads (4 waves), 32 rows per block. Grid: (N/32, B).
// ---------------------------------------------------------------------------
__global__ __launch_bounds__(256) void pass_a(
    const float* __restrict__ x, const float* __restrict__ clusters,
    const float* __restrict__ bn_weight, const float* __restrict__ bn_bias,
    const float* __restrict__ running_mean, const float* __restrict__ running_var,
    float* __restrict__ assign, float* __restrict__ a_sum)
{
    __shared__ float ldsC[128 * 80];   // clusters chunk [128 d][80 cols] (40 KB)
    __shared__ float ldsX[32 * 128];   // x rows chunk [32 rows][128 d]   (16 KB)
    __shared__ float ldsR[4 * 64];     // a_sum partials

    const int b = blockIdx.y;
    const int rowbase = blockIdx.x * 32;
    const int tid = threadIdx.x;
    const int w = tid >> 6;        // wave id 0..3
    const int lane = tid & 63;
    const int col1 = 64 + (lane & 15);
    const bool v1 = (lane < 16);

    float acc0[8], acc1[8];
#pragma unroll
    for (int r = 0; r < 8; ++r) { acc0[r] = 0.f; acc1[r] = 0.f; }

    for (int c = 0; c < 4; ++c) {
        // stage clusters chunk: 128*80 = 10240 contiguous floats
        {
            const float4* src = (const float4*)(clusters + c * 10240);
            float4* dst = (float4*)ldsC;
            for (int i = tid; i < 2560; i += 256) dst[i] = src[i];
        }
        // stage x rows: 32 rows x 128 d
        for (int i = tid; i < 1024; i += 256) {
            int row = i >> 5;            // (i*4)/128
            int dd = (i & 31) * 4;
            ((float4*)ldsX)[i] =
                *(const float4*)(x + ((size_t)(b * N + rowbase + row)) * D + c * 128 + dd);
        }
        __syncthreads();

        const float* xw = ldsX + w * 8 * 128;
        for (int dd = 0; dd < 128; dd += 2) {
            float c00 = ldsC[dd * 80 + lane];
            float c01 = ldsC[dd * 80 + 80 + lane];
            float c10 = ldsC[dd * 80 + col1];
            float c11 = ldsC[dd * 80 + 80 + col1];
#pragma unroll
            for (int r = 0; r < 8; ++r) {
                float2 xv = *(const float2*)(xw + r * 128 + dd);
                acc0[r] += xv.x * c00;
                acc0[r] += xv.y * c01;
                acc1[r] += xv.x * c10;
                acc1[r] += xv.y * c11;
            }
        }
        __syncthreads();
    }

    // BN affine params for this lane's columns
    float sc0 = bn_weight[lane] * rsqrtf(running_var[lane] + 1e-5f);
    float rm0 = running_mean[lane];
    float bb0 = bn_bias[lane];
    float sc1 = bn_weight[col1] * rsqrtf(running_var[col1] + 1e-5f);
    float rm1 = running_mean[col1];
    float bb1 = bn_bias[col1];

    float asum = 0.f;
#pragma unroll 1
    for (int r = 0; r < 8; ++r) {
        float l0 = (acc0[r] - rm0) * sc0 + bb0;
        float l1 = (acc1[r] - rm1) * sc1 + bb1;
        float m = v1 ? fmaxf(l0, l1) : l0;
#pragma unroll
        for (int o = 32; o >= 1; o >>= 1) m = fmaxf(m, __shfl_xor(m, o, 64));
        float e0 = __expf(l0 - m);
        float e1 = v1 ? __expf(l1 - m) : 0.f;
        float s = e0 + e1;
#pragma unroll
        for (int o = 32; o >= 1; o >>= 1) s += __shfl_xor(s, o, 64);
        float a0 = e0 / s;
        assign[((size_t)(b * N + rowbase + w * 8 + r)) * K + lane] = a0;
        asum += a0;
    }

    ldsR[w * 64 + lane] = asum;
    __syncthreads();
    if (w == 0) {
        float t = ldsR[lane] + ldsR[64 + lane] + ldsR[128 + lane] + ldsR[192 + lane];
        atomicAdd(&a_sum[b * K + lane], t);
    }
}

// ---------------------------------------------------------------------------
// Pass B: vlad[b,d,k] = sum_n x[b,n,d]*assign[b,n,k] - a_sum[b,k]*clusters2[d,k]
// Block: 256 threads, tile = 128 d x 64 k. Grid: (4, B).
// ---------------------------------------------------------------------------
__global__ __launch_bounds__(256) void pass_b(
    const float* __restrict__ x, const float* __restrict__ assign,
    const float* __restrict__ a_sum, const float* __restrict__ clusters2,
    float* __restrict__ vlad)
{
    __shared__ float xs[64 * 128];   // [n][d] 32 KB
    __shared__ float as_[64 * 64];   // [n][k] 16 KB

    const int b = blockIdx.y;
    const int dt = blockIdx.x;       // 0..3
    const int tid = threadIdx.x;
    const int tx = tid & 15;         // k: 4 each -> k0 = tx*4
    const int ty = tid >> 4;         // d: 8 each -> d0 = ty*8

    float acc[8][4];
#pragma unroll
    for (int i = 0; i < 8; ++i)
#pragma unroll
        for (int j = 0; j < 4; ++j) acc[i][j] = 0.f;

    for (int nc = 0; nc < N; nc += 64) {
        for (int i = tid; i < 2048; i += 256) {
            int n_l = i >> 5;            // (i*4)/128
            int dd = (i & 31) * 4;
            ((float4*)xs)[i] =
                *(const float4*)(x + ((size_t)(b * N + nc + n_l)) * D + dt * 128 + dd);
        }
        for (int i = tid; i < 1024; i += 256) {
            int n_l = i >> 4;            // (i*4)/64
            int kk = (i & 15) * 4;
            ((float4*)as_)[i] =
                *(const float4*)(assign + ((size_t)(b * N + nc + n_l)) * K + kk);
        }
        __syncthreads();

        for (int n = 0; n < 64; ++n) {
            float4 a4 = *(const float4*)(as_ + n * 64 + tx * 4);
            float4 xa = *(const float4*)(xs + n * 128 + ty * 8);
            float4 xb = *(const float4*)(xs + n * 128 + ty * 8 + 4);
            float xv[8] = {xa.x, xa.y, xa.z, xa.w, xb.x, xb.y, xb.z, xb.w};
            float av[4] = {a4.x, a4.y, a4.z, a4.w};
#pragma unroll
            for (int i = 0; i < 8; ++i)
#pragma unroll
                for (int j = 0; j < 4; ++j) acc[i][j] += xv[i] * av[j];
        }
        __syncthreads();
    }

    // epilogue: subtract a_sum*clusters2, write vlad
    float av[4];
#pragma unroll
    for (int j = 0; j < 4; ++j) av[j] = a_sum[b * K + tx * 4 + j];
#pragma unroll
    for (int i = 0; i < 8; ++i) {
        int d = dt * 128 + ty * 8 + i;
#pragma unroll
        for (int j = 0; j < 4; ++j) {
            int k = tx * 4 + j;
            float v = acc[i][j] - av[j] * clusters2[d * K + k];
            vlad[((size_t)b * D + d) * K + k] = v;
        }
    }
}

// ---------------------------------------------------------------------------
// Pass C: intra-normalize over D per (b,k), then L2-normalize [D*K] per b.
// One block per batch.
// ---------------------------------------------------------------------------
__global__ __launch_bounds__(256) void pass_c(
    const float* __restrict__ vlad, float* __restrict__ out)
{
    __shared__ float partial[256];
    __shared__ float scale_s[64];

    const int b = blockIdx.x;
    const int tid = threadIdx.x;
    const int k = tid & 63;
    const int dstart = tid >> 6;     // 0..3

    float ssq = 0.f;
    for (int d = dstart; d < D; d += 4) {
        float v = vlad[((size_t)b * D + d) * K + k];
        ssq += v * v;
    }
    partial[tid] = ssq;
    __syncthreads();

    if (tid < 64) {
        float cs = partial[k] + partial[64 + k] + partial[128 + k] + partial[192 + k];
        float cn = sqrtf(cs);
        float invc = 1.f / fmaxf(cn, 1e-12f);
        partial[k] = cs * invc * invc;   // squared norm of the normalized column
        scale_s[k] = invc;
    }
    __syncthreads();

    if (tid == 0) {
        float rs = 0.f;
        for (int k2 = 0; k2 < 64; ++k2) rs += partial[k2];
        float rn = sqrtf(rs);
        partial[0] = 1.f / fmaxf(rn, 1e-12f);
    }
    __syncthreads();
    float invr = partial[0];

    for (int i = tid; i < D * K; i += 256) {
        int kk = i & 63;
        out[(size_t)b * D * K + i] = vlad[(size_t)b * D * K + i] * scale_s[kk] * invr;
    }
}

extern "C" void kernel_launch(void* const* d_in, const int* in_sizes, int n_in,
                              void* d_out, int out_size, void* d_ws, size_t ws_size,
                              hipStream_t stream)
{
    const float* x         = (const float*)d_in[0];
    const float* clusters  = (const float*)d_in[1];
    const float* clusters2 = (const float*)d_in[2];
    const float* bn_w      = (const float*)d_in[3];
    const float* bn_b      = (const float*)d_in[4];
    const float* rmean     = (const float*)d_in[5];
    const float* rvar      = (const float*)d_in[6];
    float* out = (float*)d_out;

    char* ws = (char*)d_ws;
    float* a_sum  = (float*)ws;                           // 16 KB
    float* vlad   = (float*)(ws + 65536);                 // 8 MB
    float* assign = (float*)(ws + 65536 + 8388608);       // 32 MB

    hipMemsetAsync(a_sum, 0, B * K * sizeof(float), stream);

    pass_a<<<dim3(N / 32, B), 256, 0, stream>>>(x, clusters, bn_w, bn_b, rmean, rvar,
                                                assign, a_sum);
    pass_b<<<dim3(4, B), 256, 0, stream>>>(x, assign, a_sum, clusters2, vlad);
    pass_c<<<B, 256, 0, stream>>>(vlad, out);
}

// Round 2
// 527.037 us; speedup vs baseline: 1.9122x; 1.9122x over previous
//
#include <hip/hip_runtime.h>
#include <math.h>

#define BN 131072   // B*N total rows

typedef __attribute__((ext_vector_type(8))) short bf16x8;
typedef __attribute__((ext_vector_type(4))) float f32x4;

__device__ __forceinline__ unsigned short f2bf(float f) {
    unsigned int u = __float_as_uint(f);
    u += 0x7fffu + ((u >> 16) & 1u);      // round-to-nearest-even
    return (unsigned short)(u >> 16);
}

// ---------------------------------------------------------------------------
// prep: clusters_T[kg][d] = bf16(clusters[d][kg] * bn_scale[kg]);
//       bnadd[kg] = bias - mean*scale.  40960 elements, 160 blocks.
// ---------------------------------------------------------------------------
__global__ __launch_bounds__(256) void prep(
    const float* __restrict__ clusters, const float* __restrict__ bnw,
    const float* __restrict__ bnb, const float* __restrict__ rm,
    const float* __restrict__ rv,
    unsigned short* __restrict__ cT, float* __restrict__ bnadd)
{
    int i = blockIdx.x * 256 + threadIdx.x;      // 0..40959
    int d = i / 80;
    int kg = i - d * 80;
    float mul = bnw[kg] * rsqrtf(rv[kg] + 1e-5f);
    cT[kg * 512 + d] = f2bf(clusters[i] * mul);
    if (i < 80) bnadd[i] = bnb[i] - rm[i] * mul;
}

// ---------------------------------------------------------------------------
// pass_a: logits = x @ (clusters*sc)  via bf16 MFMA, +add, softmax over 80,
// write assign_T[64][BN] bf16, accumulate a_sum[b][64].
// Block 256 thr / 4 waves, 64 rows. Grid 2048.
// ---------------------------------------------------------------------------
__global__ __launch_bounds__(256) void pass_a(
    const float* __restrict__ x, const unsigned short* __restrict__ cT,
    const float* __restrict__ bnadd,
    unsigned short* __restrict__ assignT, float* __restrict__ a_sum)
{
    __shared__ unsigned short xs[64 * 136];   // [row][d-chunk] pad->136
    __shared__ unsigned short cs[80 * 136];   // [kg][d-chunk]

    const int tid = threadIdx.x;
    const int w = tid >> 6, lane = tid & 63;
    const int q = lane >> 4, m = lane & 15;
    const int rowbase = blockIdx.x * 64;
    const int b = rowbase >> 11;              // N = 2048

    f32x4 acc[5];
#pragma unroll
    for (int t = 0; t < 5; ++t) acc[t] = (f32x4){0.f, 0.f, 0.f, 0.f};

    for (int c = 0; c < 4; ++c) {
        // stage x chunk [64 rows][128 d], fp32 -> bf16
#pragma unroll
        for (int r = 0; r < 8; ++r) {
            int i = tid + 256 * r;            // 2048 float4
            int row = i >> 5, dd = (i & 31) * 4;
            float4 v = *(const float4*)(x + (size_t)(rowbase + row) * 512 + c * 128 + dd);
            ushort4 h = { f2bf(v.x), f2bf(v.y), f2bf(v.z), f2bf(v.w) };
            *(ushort4*)&xs[row * 136 + dd] = h;
        }
        // stage clusters_T chunk [80][128] bf16
#pragma unroll
        for (int r = 0; r < 10; ++r) {
            int i = tid + 256 * r;            // 2560 ushort4
            int kg = i >> 5, dd = (i & 31) * 4;
            ushort4 h = *(const ushort4*)(cT + kg * 512 + c * 128 + dd);
            *(ushort4*)&cs[kg * 136 + dd] = h;
        }
        __syncthreads();
#pragma unroll
        for (int ks = 0; ks < 4; ++ks) {
            bf16x8 a = *(const bf16x8*)&xs[(w * 16 + m) * 136 + ks * 32 + q * 8];
#pragma unroll
            for (int t = 0; t < 5; ++t) {
                bf16x8 bb = *(const bf16x8*)&cs[(m + 16 * t) * 136 + ks * 32 + q * 8];
                acc[t] = __builtin_amdgcn_mfma_f32_16x16x32_bf16(a, bb, acc[t], 0, 0, 0);
            }
        }
        __syncthreads();
    }

    float addv[5];
#pragma unroll
    for (int t = 0; t < 5; ++t) addv[t] = bnadd[m + 16 * t];

    // softmax over 80: row i lives in 16 lanes (same quad) x 5 tiles
    float e[5][4], rs[4];
#pragma unroll
    for (int i = 0; i < 4; ++i) {
        float v[5];
#pragma unroll
        for (int t = 0; t < 5; ++t) v[t] = acc[t][i] + addv[t];
        float mx = v[0];
#pragma unroll
        for (int t = 1; t < 5; ++t) mx = fmaxf(mx, v[t]);
        mx = fmaxf(mx, __shfl_xor(mx, 1, 64));
        mx = fmaxf(mx, __shfl_xor(mx, 2, 64));
        mx = fmaxf(mx, __shfl_xor(mx, 4, 64));
        mx = fmaxf(mx, __shfl_xor(mx, 8, 64));
        float s = 0.f;
#pragma unroll
        for (int t = 0; t < 5; ++t) { e[t][i] = __expf(v[t] - mx); s += e[t][i]; }
        s += __shfl_xor(s, 1, 64);
        s += __shfl_xor(s, 2, 64);
        s += __shfl_xor(s, 4, 64);
        s += __shfl_xor(s, 8, 64);
        rs[i] = 1.0f / s;
    }

    const int n0 = rowbase + w * 16 + q * 4;
#pragma unroll
    for (int t = 0; t < 4; ++t) {
        float a0 = e[t][0] * rs[0], a1 = e[t][1] * rs[1];
        float a2 = e[t][2] * rs[2], a3 = e[t][3] * rs[3];
        ushort4 h = { f2bf(a0), f2bf(a1), f2bf(a2), f2bf(a3) };
        *(ushort4*)(assignT + (size_t)(m + 16 * t) * BN + n0) = h;
        float as = a0 + a1 + a2 + a3;
        as += __shfl_xor(as, 16, 64);
        as += __shfl_xor(as, 32, 64);
        if (lane < 16) atomicAdd(&a_sum[b * 64 + m + 16 * t], as);
    }
}

// ---------------------------------------------------------------------------
// pass_b: vlad[b][d][kc] = sum_n x[b,n,d]*assign[b,n,kc] - a_sum*clusters2.
// A = x^T (transposed LDS u16 reads), B = assign_T (clean b128 reads).
// Block 256 thr / 4 waves: tile 64 d x 64 kc; grid (8 d-tiles, 64 b).
// ---------------------------------------------------------------------------
__global__ __launch_bounds__(256) void pass_b(
    const float* __restrict__ x, const unsigned short* __restrict__ assignT,
    const float* __restrict__ a_sum, const float* __restrict__ clusters2,
    float* __restrict__ vlad, float* __restrict__ colssq)
{
    __shared__ unsigned short xs2[64 * 130];  // [n][d] pad->130 (quad bank spread)
    __shared__ unsigned short as2[64 * 72];   // [kc][n] pad->72 (b128 aligned)

    const int tid = threadIdx.x;
    const int w = tid >> 6, lane = tid & 63;
    const int q = lane >> 4, m = lane & 15;
    const int dt = blockIdx.x;                // 0..7
    const int b = blockIdx.y;

    f32x4 acc[4];
#pragma unroll
    for (int t = 0; t < 4; ++t) acc[t] = (f32x4){0.f, 0.f, 0.f, 0.f};

    for (int nc = 0; nc < 2048; nc += 64) {
        // stage x chunk [64 n][64 d] fp32 -> bf16 LDS
#pragma unroll
        for (int r = 0; r < 4; ++r) {
            int i = tid + 256 * r;            // 1024 float4
            int nl = i >> 4, dd = (i & 15) * 4;
            float4 v = *(const float4*)(x + (size_t)(b * 2048 + nc + nl) * 512 + dt * 64 + dd);
            unsigned int lo = (unsigned int)f2bf(v.x) | ((unsigned int)f2bf(v.y) << 16);
            unsigned int hi = (unsigned int)f2bf(v.z) | ((unsigned int)f2bf(v.w) << 16);
            *(unsigned int*)&xs2[nl * 130 + dd] = lo;
            *(unsigned int*)&xs2[nl * 130 + dd + 2] = hi;
        }
        // stage assign_T chunk [64 kc][64 n]
#pragma unroll
        for (int r = 0; r < 4; ++r) {
            int i = tid + 256 * r;            // 1024 ushort4
            int kc = i >> 4, nl = (i & 15) * 4;
            ushort4 h = *(const ushort4*)(assignT + (size_t)kc * BN + b * 2048 + nc + nl);
            *(ushort4*)&as2[kc * 72 + nl] = h;
        }
        __syncthreads();
#pragma unroll
        for (int ks = 0; ks < 2; ++ks) {
            union { unsigned short u[8]; bf16x8 v; } af;
            const int dcol = w * 16 + m;
#pragma unroll
            for (int j = 0; j < 8; ++j)
                af.u[j] = xs2[(ks * 32 + q * 8 + j) * 130 + dcol];
#pragma unroll
            for (int nt = 0; nt < 4; ++nt) {
                bf16x8 bb = *(const bf16x8*)&as2[(nt * 16 + m) * 72 + ks * 32 + q * 8];
                acc[nt] = __builtin_amdgcn_mfma_f32_16x16x32_bf16(af.v, bb, acc[nt], 0, 0, 0);
            }
        }
        __syncthreads();
    }

    const int d0 = dt * 64 + w * 16 + q * 4;
#pragma unroll
    for (int nt = 0; nt < 4; ++nt) {
        int kc = nt * 16 + m;
        float asv = a_sum[b * 64 + kc];
        float ss = 0.f;
#pragma unroll
        for (int i = 0; i < 4; ++i) {
            int d = d0 + i;
            float v = acc[nt][i] - asv * clusters2[d * 64 + kc];
            vlad[((size_t)b * 512 + d) * 64 + kc] = v;
            ss += v * v;
        }
        ss += __shfl_xor(ss, 16, 64);
        ss += __shfl_xor(ss, 32, 64);
        if (lane < 16) atomicAdd(&colssq[b * 64 + kc], ss);
    }
}

// ---------------------------------------------------------------------------
// pass_c: per-column scale from colssq, global scale, write out.
// Grid (8 segs, 64 b).
// ---------------------------------------------------------------------------
__global__ __launch_bounds__(256) void pass_c(
    const float* __restrict__ vlad, const float* __restrict__ colssq,
    float* __restrict__ out)
{
    __shared__ float sc[65];
    const int b = blockIdx.y, seg = blockIdx.x, tid = threadIdx.x;

    if (tid < 64) {
        float css = colssq[b * 64 + tid];
        float invc = 1.0f / fmaxf(sqrtf(css), 1e-12f);
        sc[tid] = invc;
        float ns = css * invc * invc;     // squared norm of normalized column
        ns += __shfl_xor(ns, 1, 64);
        ns += __shfl_xor(ns, 2, 64);
        ns += __shfl_xor(ns, 4, 64);
        ns += __shfl_xor(ns, 8, 64);
        ns += __shfl_xor(ns, 16, 64);
        ns += __shfl_xor(ns, 32, 64);
        if (tid == 0) sc[64] = 1.0f / fmaxf(sqrtf(ns), 1e-12f);
    }
    __syncthreads();
    const float invr = sc[64];

#pragma unroll
    for (int r = 0; r < 4; ++r) {
        int i4 = seg * 1024 + r * 256 + tid;
        float4 v = *(const float4*)(vlad + (size_t)b * 32768 + (size_t)i4 * 4);
        int c0 = (i4 & 15) * 4;
        float4 o;
        o.x = v.x * sc[c0 + 0] * invr;
        o.y = v.y * sc[c0 + 1] * invr;
        o.z = v.z * sc[c0 + 2] * invr;
        o.w = v.w * sc[c0 + 3] * invr;
        *(float4*)(out + (size_t)b * 32768 + (size_t)i4 * 4) = o;
    }
}

extern "C" void kernel_launch(void* const* d_in, const int* in_sizes, int n_in,
                              void* d_out, int out_size, void* d_ws, size_t ws_size,
                              hipStream_t stream)
{
    const float* x         = (const float*)d_in[0];
    const float* clusters  = (const float*)d_in[1];
    const float* clusters2 = (const float*)d_in[2];
    const float* bn_w      = (const float*)d_in[3];
    const float* bn_b      = (const float*)d_in[4];
    const float* rmean     = (const float*)d_in[5];
    const float* rvar      = (const float*)d_in[6];
    float* out = (float*)d_out;

    char* ws = (char*)d_ws;
    float* a_sum            = (float*)(ws + 0);            // 16 KB
    float* colssq           = (float*)(ws + 16384);        // 16 KB
    float* bnadd            = (float*)(ws + 32768);        // 320 B
    unsigned short* cT      = (unsigned short*)(ws + 65536);       // 80 KB
    unsigned short* assignT = (unsigned short*)(ws + 262144);      // 16 MB
    float* vlad             = (float*)(ws + 262144 + 16777216);    // 8 MB

    hipMemsetAsync(ws, 0, 32768, stream);   // a_sum + colssq

    prep<<<160, 256, 0, stream>>>(clusters, bn_w, bn_b, rmean, rvar, cT, bnadd);
    pass_a<<<2048, 256, 0, stream>>>(x, cT, bnadd, assignT, a_sum);
    pass_b<<<dim3(8, 64), 256, 0, stream>>>(x, assignT, a_sum, clusters2, vlad, colssq);
    pass_c<<<dim3(8, 64), 256, 0, stream>>>(vlad, colssq, out);
}